// Round 12
// baseline (384.053 us; speedup 1.0000x reference)
//
#include <hip/hip_runtime.h>
#include <math.h>

#define Bv   64
#define Nv   900
#define Mv   64
#define NCls 128
#define NCOLS (Nv + 1)          // 901 columns incl. dummy col 0
#define KREG 15                 // columns per lane: j = t + 64k, k=0..14
#define ARR_CAP 160             // safety cap on ARR steps (termination bound)
#define INFV 1000000000.0f
#define BIGV 1.0e18f            // sentinel for used/invalid slots

// uniform dynamic read (serial chain; only in the rare backtrack)
#define SEL15(arr, kidx, dst) do {            \
    int _s = arr[0];                          \
    _Pragma("unroll")                         \
    for (int _kk = 1; _kk < KREG; _kk++)      \
        _s = ((kidx) == _kk) ? arr[_kk] : _s; \
    (dst) = _s;                               \
} while (0)

// binary-tree select (depth 4). kidx may be PER-LANE. HW-verified R7-R10.
#define SELTREE15(arr, kidx, dst) do {                      \
    int _a0 = ((kidx) & 1) ? arr[1]  : arr[0];              \
    int _a1 = ((kidx) & 1) ? arr[3]  : arr[2];              \
    int _a2 = ((kidx) & 1) ? arr[5]  : arr[4];              \
    int _a3 = ((kidx) & 1) ? arr[7]  : arr[6];              \
    int _a4 = ((kidx) & 1) ? arr[9]  : arr[8];              \
    int _a5 = ((kidx) & 1) ? arr[11] : arr[10];             \
    int _a6 = ((kidx) & 1) ? arr[13] : arr[12];             \
    int _a7 = arr[14];          /* k==15 never occurs */    \
    int _b0 = ((kidx) & 2) ? _a1 : _a0;                     \
    int _b1 = ((kidx) & 2) ? _a3 : _a2;                     \
    int _b2 = ((kidx) & 2) ? _a5 : _a4;                     \
    int _b3 = ((kidx) & 2) ? _a7 : _a6;                     \
    int _c0 = ((kidx) & 4) ? _b1 : _b0;                     \
    int _c1 = ((kidx) & 4) ? _b3 : _b2;                     \
    (dst)   = ((kidx) & 8) ? _c1 : _c0;                     \
} while (0)

// uniform dynamic write (lane-targeted)
#define SET15(arr, kidx, val) do {            \
    _Pragma("unroll")                         \
    for (int _kk = 0; _kk < KREG; _kk++)      \
        if ((kidx) == _kk) arr[_kk] = (val);  \
} while (0)

// ---- order-preserving float <-> sortable u32 (bit-exact round trip) --------
__device__ __forceinline__ unsigned f2s(float f) {
    unsigned x = __float_as_uint(f);
    return x ^ ((unsigned)((int)x >> 31) | 0x80000000u);
}
__device__ __forceinline__ float s2f(unsigned s) {
    unsigned x = ((int)s < 0) ? (s ^ 0x80000000u) : ~s;
    return __uint_as_float(x);
}

// ---- wave64 min-reduce of packed (hi=sortable value, lo) via DPP -----------
// HW-verified R4/R7/R10. Lexicographic (value, lo); lo = (j<<7)|p[j] gives
// exact first-j tie-break (p is a function of j).
__device__ __forceinline__ void wave_min_pair(unsigned& hi, unsigned& lo) {
#define DPP_STEP(ctrl, rmask)                                                   \
    {                                                                           \
        unsigned ohi = (unsigned)__builtin_amdgcn_update_dpp(                   \
            (int)hi, (int)hi, ctrl, rmask, 0xf, false);                         \
        unsigned olo = (unsigned)__builtin_amdgcn_update_dpp(                   \
            (int)lo, (int)lo, ctrl, rmask, 0xf, false);                         \
        bool take = (ohi < hi) || (ohi == hi && olo < lo);                      \
        hi = take ? ohi : hi;                                                   \
        lo = take ? olo : lo;                                                   \
    }
    DPP_STEP(0x111, 0xf)   // row_shr:1
    DPP_STEP(0x112, 0xf)   // row_shr:2
    DPP_STEP(0x114, 0xf)   // row_shr:4
    DPP_STEP(0x118, 0xf)   // row_shr:8
    DPP_STEP(0x142, 0xa)   // row_bcast:15
    DPP_STEP(0x143, 0xc)   // row_bcast:31 -> lane 63 holds min
#undef DPP_STEP
    hi = (unsigned)__builtin_amdgcn_readlane((int)hi, 63);
    lo = (unsigned)__builtin_amdgcn_readlane((int)lo, 63);
}

__device__ __forceinline__ float wave_sum_f32(float x) {
#define SSTEP(ctrl, rmask)                                                \
    {                                                                     \
        int o = __builtin_amdgcn_update_dpp(0, __float_as_int(x),         \
                                            ctrl, rmask, 0xf, false);     \
        x += __int_as_float(o);                                           \
    }
    SSTEP(0x111, 0xf) SSTEP(0x112, 0xf) SSTEP(0x114, 0xf) SSTEP(0x118, 0xf)
    SSTEP(0x142, 0xa) SSTEP(0x143, 0xc)
#undef SSTEP
    return __int_as_float(__builtin_amdgcn_readlane(__float_as_int(x), 63));
}

// ---------------------------------------------------------------------------
// Kernel 1: cost matrix. 4 waves/block, one n per wave (verified R6).
// ---------------------------------------------------------------------------
__global__ __launch_bounds__(256) void cost_kernel(
    const float* __restrict__ logits,   // [B,N,128]
    const float* __restrict__ corners,  // [B,N,8,3]
    const int*   __restrict__ labels,   // [B,64]
    const float* __restrict__ boxes,    // [B,64,7]
    float*       __restrict__ C)        // [B,N,64]
{
    const int b = blockIdx.y;
    const int n = blockIdx.x * 4 + (threadIdx.x >> 6);
    const int t = threadIdx.x & 63;
    const long bn = (long)b * Nv + n;

    const float2 l2 = ((const float2*)(logits + bn * NCls))[t];
    const float* cp = corners + bn * 24;
    float cx = 0.f, cy = 0.f, cz = 0.f;
    if (t < 8) { cx = cp[3 * t]; cy = cp[3 * t + 1]; cz = cp[3 * t + 2]; }
    const int    lbl = labels[b * Mv + t];
    const float* bx  = boxes + ((long)b * Mv + t) * 7;
    const float bx0 = bx[0], bx1 = bx[1], bx2 = bx[2];

    float e0 = expf(l2.x), e1 = expf(l2.y);
    float s  = wave_sum_f32(e0 + e1);

    cx = wave_sum_f32(cx) * 0.125f;
    cy = wave_sum_f32(cy) * 0.125f;
    cz = wave_sum_f32(cz) * 0.125f;

    float p0 = __shfl(e0, lbl >> 1, 64);
    float p1 = __shfl(e1, lbl >> 1, 64);
    float pm = ((lbl & 1) ? p1 : p0) / s;

    float dx = cx - bx0, dy = cy - bx1, dz = cz - bx2;
    C[bn * Mv + t] = 5.0f * sqrtf(dx * dx + dy * dy + dz * dz) - pm;
}

// ---------------------------------------------------------------------------
// Kernel 2: LAPJV-style LSA. Fetch/compute structure = R10 EXACTLY (verified
// 148us; R11's LDS cache and all other fetch restructures regressed — the
// ~530cy/iter floor is TA gather-issue throughput, untouchable at fixed
// layout). R12 attacks ITERATION COUNT instead: LAPJV augmenting row
// reduction (ARR) between Phase B and the Dijkstra loop. Per free row:
// min1/min2 of reduced row r_j = c[i][j] - v[j]; u[i]=min2; if min1<min2
// strictly, v[j1] -= (min2-min1) and take j1 (stealing its owner); on exact
// tie take j1 if free else j2. Invariant maintained exactly: duals feasible
// (c-u-v>=0 everywhere) + all matched edges tight => subsequent SSP/Dijkstra
// phases (unchanged code) are exactly optimal. ARR_CAP bounds steps;
// leftovers fall through to the verified Dijkstra path.
// ---------------------------------------------------------------------------
__global__ __launch_bounds__(64) void lsa_kernel(
    const float* __restrict__ C,    // [B, N, M] = [64,900,64]
    float* __restrict__ outPred, float* __restrict__ outTgt)
{
    const int b = blockIdx.x;
    const int t = threadIdx.x;
    const float* cb = C + (size_t)b * Nv * Mv;

    // ---- Phase A: row argmin (lane t = row t+1); 4 ranges, deep unroll
    float mv0 = INFV, mv1 = INFV, mv2 = INFV, mv3 = INFV;
    int   mj0 = 0,    mj1 = 0,    mj2 = 0,    mj3 = 0;
    #pragma unroll 9
    for (int n = 0; n < 225; ++n) {
        float c0 = cb[(size_t)(n      ) * Mv + t];
        float c1 = cb[(size_t)(n + 225) * Mv + t];
        float c2 = cb[(size_t)(n + 450) * Mv + t];
        float c3 = cb[(size_t)(n + 675) * Mv + t];
        if (c0 < mv0) { mv0 = c0; mj0 = n;       }
        if (c1 < mv1) { mv1 = c1; mj1 = n + 225; }
        if (c2 < mv2) { mv2 = c2; mj2 = n + 450; }
        if (c3 < mv3) { mv3 = c3; mj3 = n + 675; }
    }
    float rowmin = mv0; int rown = mj0;
    if (mv1 < rowmin) { rowmin = mv1; rown = mj1; }
    if (mv2 < rowmin) { rowmin = mv2; rown = mj2; }
    if (mv3 < rowmin) { rowmin = mv3; rown = mj3; }

    float u_reg = rowmin;            // lane l holds u[l+1]
    const int jcol = rown + 1;       // column index in 1..900

    // ---- Phase B: duplicate detection (first occurrence wins)
    bool isdup = false;
    #pragma unroll
    for (int s = 1; s < 64; ++s) {
        int oj = __shfl(jcol, (t + 64 - s) & 63, 64);
        isdup |= (oj == jcol) && (s <= t);
    }
    unsigned long long pending = __ballot(isdup);

    int   p_reg[KREG], way_reg[KREG];
    float v_reg[KREG], minv[KREG], crow[KREG];
    #pragma unroll
    for (int k = 0; k < KREG; k++) { p_reg[k] = 0; way_reg[k] = 0; v_reg[k] = 0.f; }

    int rowcol = isdup ? 0 : jcol;   // lane i: column assigned to row i+1

    // scatter winners into distributed p[]
    #pragma unroll 8
    for (int i = 0; i < 64; ++i) {
        int jb = __shfl(jcol, i, 64);
        if (!((pending >> i) & 1ull) && t == (jb & 63))
            SET15(p_reg, jb >> 6, i + 1);
    }

    // ---- Phase B2: LAPJV augmenting row reduction (ARR)
    // Each step: one gather + two packed reduces + O(1) register updates.
    // Maintains duals-feasible + matched-tight exactly (see header comment).
    int steps = 0;
    while (pending && steps < ARR_CAP) {
        ++steps;
        const int iv = __ffsll(pending);     // 1-based free row
        pending &= pending - 1;

        // gather row iv (j==0 / out-of-range -> BIGV)
        #pragma unroll
        for (int k = 0; k < KREG; k++) {
            int j = t + (k << 6);
            crow[k] = (j >= 1 && j < NCOLS)
                      ? cb[(((size_t)(j - 1)) << 6) + (iv - 1)] : BIGV;
        }

        // per-lane reduced costs + min; stash r in minv[] scratch
        float m1l = BIGV; int k1l = 0;
        #pragma unroll
        for (int k = 0; k < KREG; k++) {
            float r = crow[k] - v_reg[k];
            minv[k] = r;
            if (r < m1l) { m1l = r; k1l = k; }
        }
        // global min1 with (j, p[j]) packed (R10-verified fused reduce)
        int pc1; SELTREE15(p_reg, k1l, pc1);
        unsigned h1 = f2s(m1l);
        unsigned o1 = ((unsigned)(t + (k1l << 6)) << 7) | (unsigned)pc1;
        wave_min_pair(h1, o1);
        const float min1 = s2f(h1);
        const int   j1   = (int)(o1 >> 7);
        const int   own1 = (int)(o1 & 0x7fu);
        const int   k1   = j1 >> 6, l1 = j1 & 63;

        // global second-min: mask the single global (l1,k1) slot
        float m2l = BIGV; int k2l = 0;
        #pragma unroll
        for (int k = 0; k < KREG; k++) {
            float r = ((t == l1) && (k == k1)) ? BIGV : minv[k];
            if (r < m2l) { m2l = r; k2l = k; }
        }
        int pc2; SELTREE15(p_reg, k2l, pc2);
        unsigned h2 = f2s(m2l);
        unsigned o2 = ((unsigned)(t + (k2l << 6)) << 7) | (unsigned)pc2;
        wave_min_pair(h2, o2);
        const float min2 = s2f(h2);
        const int   j2   = (int)(o2 >> 7);
        const int   own2 = (int)(o2 & 0x7fu);

        // choose target column (tie -> j1 only if free, else j2; avoids
        // ping-pong cycles; exact ties ~never occur on continuous data)
        const bool strict = (min1 < min2);
        const int jt   = (strict || own1 == 0) ? j1 : j2;
        const int ownt = (strict || own1 == 0) ? own1 : own2;

        // duals: u[iv] = min2; compensate v[j1] only in the strict case
        if (t == iv - 1) u_reg = min2;
        if (strict && t == l1) v_reg[k1] -= (min2 - min1);

        // steal + assign
        if (ownt != 0) {
            pending |= 1ull << (ownt - 1);
            if (t == ownt - 1) rowcol = 0;
        }
        const int kt = jt >> 6, lt = jt & 63;
        if (t == lt) SET15(p_reg, kt, iv);
        if (t == iv - 1) rowcol = jt;
    }

    // ---- Phase C: Dijkstra phases for remaining free rows (R10-verified)
    while (pending) {
        const int i1v = __ffsll(pending);    // 1-based free row
        pending &= pending - 1;

        unsigned usedMask = (t == 0) ? 1u : 0u;   // dummy col 0 used
        unsigned long long rowMask = 0;
        #pragma unroll
        for (int k = 0; k < KREG; k++) minv[k] = INFV;

        int j0 = 0;
        int i0 = i1v;

        // initial gather for row i0; j==0 and j>=NCOLS slots get BIGV
        #pragma unroll
        for (int k = 0; k < KREG; k++) {
            int j = t + (k << 6);
            crow[k] = (j >= 1 && j < NCOLS)
                      ? cb[(((size_t)(j - 1)) << 6) + (i0 - 1)] : BIGV;
        }

        while (true) {
            rowMask |= 1ull << (i0 - 1);
            const int sl = __builtin_amdgcn_readfirstlane(i0 - 1);
            const float u_i0 = __int_as_float(
                __builtin_amdgcn_readlane(__float_as_int(u_reg), sl));

            // scan: sentinel-masked (R6-verified), 3-way split (R8-verified)
            float bv0 = INFV, bv1 = INFV, bv2 = INFV;
            int   bk0 = 0,    bk1 = 5,    bk2 = 10;
            #pragma unroll
            for (int k = 0; k < 5; k++) {
                float cur = (crow[k] - u_i0) - v_reg[k];
                if (cur < minv[k]) { minv[k] = cur; way_reg[k] = j0; }
                if (minv[k] < bv0) { bv0 = minv[k]; bk0 = k; }
            }
            #pragma unroll
            for (int k = 5; k < 10; k++) {
                float cur = (crow[k] - u_i0) - v_reg[k];
                if (cur < minv[k]) { minv[k] = cur; way_reg[k] = j0; }
                if (minv[k] < bv1) { bv1 = minv[k]; bk1 = k; }
            }
            #pragma unroll
            for (int k = 10; k < KREG; k++) {
                float cur = (crow[k] - u_i0) - v_reg[k];
                if (cur < minv[k]) { minv[k] = cur; way_reg[k] = j0; }
                if (minv[k] < bv2) { bv2 = minv[k]; bk2 = k; }
            }
            if (bv1 < bv0) { bv0 = bv1; bk0 = bk1; }
            if (bv2 < bv0) { bv0 = bv2; bk0 = bk2; }

            // fused packed reduce (R10-verified): delta, j1, inext at once
            int pcand; SELTREE15(p_reg, bk0, pcand);
            unsigned hi = f2s(bv0);
            unsigned lo = ((unsigned)(t + (bk0 << 6)) << 7) | (unsigned)pcand;
            wave_min_pair(hi, lo);
            const float delta = s2f(hi);
            const int   j1    = (int)(lo >> 7);
            const int   inext = (int)(lo & 0x7fu);

            const int k1 = j1 >> 6, l1 = j1 & 63;   // uniform (SGPR)

            // prefetch next row: RAW loads only (R7/R8 lesson) — vmcnt sinks
            // into the next scan, covered by the update pass below.
            const bool newbit = (t == l1);
            unsigned newUsed = usedMask | (newbit ? (1u << k1) : 0u);
            if (inext != 0) {
                const int src = inext - 1;
                #pragma unroll
                for (int k = 0; k < KREG; k++) {
                    int j = t + (k << 6);
                    bool valid = (j >= 1 && j < NCOLS) && !((newUsed >> k) & 1u);
                    crow[k] = valid
                              ? cb[(((size_t)(j - 1)) << 6) + src] : BIGV;
                }
            }

            // dual/distance updates (reference order; latency cover)
            if ((rowMask >> t) & 1ull) u_reg += delta;
            #pragma unroll
            for (int k = 0; k < KREG; k++) {
                bool used  = (usedMask >> k) & 1u;
                bool isnew = newbit && (k == k1);
                v_reg[k] = used ? v_reg[k] - delta : v_reg[k];
                float mupd = used ? minv[k] : minv[k] - delta;
                minv[k] = isnew ? INFV : mupd;
            }
            usedMask = newUsed;

            j0 = j1;
            i0 = inext;
            if (i0 == 0) break;              // free column reached
        }

        // backtrack: reassign columns along augmenting path
        while (j0 != 0) {
            const int k0 = j0 >> 6, l0 = j0 & 63;
            int wtmp; SEL15(way_reg, k0, wtmp);
            const int jprev = __shfl(wtmp, l0, 64);
            int pv;
            if (jprev == 0) {
                pv = i1v;
            } else {
                int ptmp2; SEL15(p_reg, jprev >> 6, ptmp2);
                pv = __shfl(ptmp2, jprev & 63, 64);
            }
            if (t == l0) SET15(p_reg, k0, pv);
            if (t == pv - 1) rowcol = j0;    // maintain row->column mirror
            j0 = jprev;
        }
    }

    outPred[b * Mv + t] = (float)(rowcol - 1);
    outTgt[b * Mv + t]  = (float)t;
}

// ---------------------------------------------------------------------------
extern "C" void kernel_launch(void* const* d_in, const int* in_sizes, int n_in,
                              void* d_out, int out_size, void* d_ws, size_t ws_size,
                              hipStream_t stream)
{
    (void)in_sizes; (void)n_in; (void)out_size; (void)d_ws; (void)ws_size;

    const float* logits  = (const float*)d_in[0];   // [64,900,128] f32
    const float* corners = (const float*)d_in[1];   // [64,900,8,3] f32
    const int*   labels  = (const int*)  d_in[2];   // [64,64] i32
    const float* boxes   = (const float*)d_in[3];   // [64,64,7] f32

    float* out  = (float*)d_out;
    float* Cc   = out;                               // [64,900,64]
    float* pred = out + (size_t)Bv * Nv * Mv;        // [64,64] as f32
    float* tgt  = pred + (size_t)Bv * Mv;            // [64,64] as f32

    cost_kernel<<<dim3(225, Bv), 256, 0, stream>>>(logits, corners, labels, boxes, Cc);
    lsa_kernel<<<Bv, 64, 0, stream>>>(Cc, pred, tgt);
}

// Round 13
// 236.108 us; speedup vs baseline: 1.6266x; 1.6266x over previous
//
#include <hip/hip_runtime.h>
#include <math.h>

#define Bv   64
#define Nv   900
#define Mv   64
#define NCls 128
#define NCOLS (Nv + 1)          // 901 columns incl. dummy col 0
#define KREG 15                 // columns per lane: j = t + 64k, k=0..14
#define INFV 1000000000.0f
#define BIGV 1.0e18f            // sentinel for used/invalid slots

// uniform dynamic read (serial chain; only in the rare backtrack)
#define SEL15(arr, kidx, dst) do {            \
    int _s = arr[0];                          \
    _Pragma("unroll")                         \
    for (int _kk = 1; _kk < KREG; _kk++)      \
        _s = ((kidx) == _kk) ? arr[_kk] : _s; \
    (dst) = _s;                               \
} while (0)

// binary-tree select (depth 4). kidx may be PER-LANE. HW-verified R7-R10.
#define SELTREE15(arr, kidx, dst) do {                      \
    int _a0 = ((kidx) & 1) ? arr[1]  : arr[0];              \
    int _a1 = ((kidx) & 1) ? arr[3]  : arr[2];              \
    int _a2 = ((kidx) & 1) ? arr[5]  : arr[4];              \
    int _a3 = ((kidx) & 1) ? arr[7]  : arr[6];              \
    int _a4 = ((kidx) & 1) ? arr[9]  : arr[8];              \
    int _a5 = ((kidx) & 1) ? arr[11] : arr[10];             \
    int _a6 = ((kidx) & 1) ? arr[13] : arr[12];             \
    int _a7 = arr[14];          /* k==15 never occurs */    \
    int _b0 = ((kidx) & 2) ? _a1 : _a0;                     \
    int _b1 = ((kidx) & 2) ? _a3 : _a2;                     \
    int _b2 = ((kidx) & 2) ? _a5 : _a4;                     \
    int _b3 = ((kidx) & 2) ? _a7 : _a6;                     \
    int _c0 = ((kidx) & 4) ? _b1 : _b0;                     \
    int _c1 = ((kidx) & 4) ? _b3 : _b2;                     \
    (dst)   = ((kidx) & 8) ? _c1 : _c0;                     \
} while (0)

// uniform dynamic write (lane-targeted)
#define SET15(arr, kidx, val) do {            \
    _Pragma("unroll")                         \
    for (int _kk = 0; _kk < KREG; _kk++)      \
        if ((kidx) == _kk) arr[_kk] = (val);  \
} while (0)

// ---- order-preserving float <-> sortable u32 (bit-exact round trip) --------
__device__ __forceinline__ unsigned f2s(float f) {
    unsigned x = __float_as_uint(f);
    return x ^ ((unsigned)((int)x >> 31) | 0x80000000u);
}
__device__ __forceinline__ float s2f(unsigned s) {
    unsigned x = ((int)s < 0) ? (s ^ 0x80000000u) : ~s;
    return __uint_as_float(x);
}

// ---- wave64 min-reduce of packed (hi=sortable value, lo) via DPP -----------
// HW-verified R4/R7/R10. Lexicographic (value, lo); lo = (j<<7)|p[j] gives
// exact first-j tie-break (p is a function of j).
__device__ __forceinline__ void wave_min_pair(unsigned& hi, unsigned& lo) {
#define DPP_STEP(ctrl, rmask)                                                   \
    {                                                                           \
        unsigned ohi = (unsigned)__builtin_amdgcn_update_dpp(                   \
            (int)hi, (int)hi, ctrl, rmask, 0xf, false);                         \
        unsigned olo = (unsigned)__builtin_amdgcn_update_dpp(                   \
            (int)lo, (int)lo, ctrl, rmask, 0xf, false);                         \
        bool take = (ohi < hi) || (ohi == hi && olo < lo);                      \
        hi = take ? ohi : hi;                                                   \
        lo = take ? olo : lo;                                                   \
    }
    DPP_STEP(0x111, 0xf)   // row_shr:1
    DPP_STEP(0x112, 0xf)   // row_shr:2
    DPP_STEP(0x114, 0xf)   // row_shr:4
    DPP_STEP(0x118, 0xf)   // row_shr:8
    DPP_STEP(0x142, 0xa)   // row_bcast:15
    DPP_STEP(0x143, 0xc)   // row_bcast:31 -> lane 63 holds min
#undef DPP_STEP
    hi = (unsigned)__builtin_amdgcn_readlane((int)hi, 63);
    lo = (unsigned)__builtin_amdgcn_readlane((int)lo, 63);
}

// ---------------------------------------------------------------------------
// Kernel 1: cost matrix — R1 VERBATIM. A/B evidence across 12 rounds:
// cost-v1 era residual (total - lsa) = 67us (R1; R2 = 67+26 transpose);
// cost-v3 era (R5-R12) = 85-90us over eight rounds. The "optimized" DPP
// wave-sum version is ~20us SLOWER (4 dependent 6-step DPP chains per wave
// serialize worse than this LDS+shfl mix). Reverted; single-variable round.
// ---------------------------------------------------------------------------
__global__ __launch_bounds__(64) void cost_kernel(
    const float* __restrict__ logits,   // [B,N,128]
    const float* __restrict__ corners,  // [B,N,8,3]
    const int*   __restrict__ labels,   // [B,64]
    const float* __restrict__ boxes,    // [B,64,7]
    float*       __restrict__ C)        // [B,N,64]
{
    const int n = blockIdx.x, b = blockIdx.y, t = threadIdx.x;
    const long bn = (long)b * Nv + n;

    // softmax numerators: lane t handles classes 2t, 2t+1 (contiguous float2)
    const float2 l2 = ((const float2*)(logits + bn * NCls))[t];
    float e0 = expf(l2.x), e1 = expf(l2.y);

    __shared__ float probs[NCls];
    ((float2*)probs)[t] = make_float2(e0, e1);

    float s = e0 + e1;
    #pragma unroll
    for (int off = 1; off < 64; off <<= 1) s += __shfl_xor(s, off, 64);

    // center = mean over 8 corners
    const float* cp = corners + bn * 24;
    float cx = 0.f, cy = 0.f, cz = 0.f;
    if (t < 8) { cx = cp[3 * t]; cy = cp[3 * t + 1]; cz = cp[3 * t + 2]; }
    #pragma unroll
    for (int off = 1; off < 8; off <<= 1) {
        cx += __shfl_xor(cx, off, 64);
        cy += __shfl_xor(cy, off, 64);
        cz += __shfl_xor(cz, off, 64);
    }
    cx = __shfl(cx, 0, 64) * 0.125f;
    cy = __shfl(cy, 0, 64) * 0.125f;
    cz = __shfl(cz, 0, 64) * 0.125f;

    __syncthreads();   // probs visible

    int lbl = labels[b * Mv + t];
    float pm = probs[lbl] / s;
    const float* bx = boxes + ((long)b * Mv + t) * 7;
    float dx = cx - bx[0], dy = cy - bx[1], dz = cz - bx[2];
    float d = sqrtf(dx * dx + dy * dy + dz * dz);

    C[bn * Mv + t] = 5.0f * d - pm;
}

// ---------------------------------------------------------------------------
// Kernel 2: LAPJV-style LSA — R10 VERBATIM (verified 148.0us). Every attack
// axis is empirically closed: VALU cuts null (R9/R10 — slack proven), fetch
// restructures regressed (R2/R3/R4/R8/R11), Delta-form regressed (R7), ARR
// iteration-count reduction regressed (R12 — conflict depth is intrinsic to
// the clustered geometry). Floor = ~670 serial iterations x ~530cy of TA
// gather-issue throughput (960 distinct lines/iter @ ~2 req/cy), VALU and
// reduce fully hidden underneath. Do not touch.
// ---------------------------------------------------------------------------
__global__ __launch_bounds__(64) void lsa_kernel(
    const float* __restrict__ C,    // [B, N, M] = [64,900,64]
    float* __restrict__ outPred, float* __restrict__ outTgt)
{
    const int b = blockIdx.x;
    const int t = threadIdx.x;
    const float* cb = C + (size_t)b * Nv * Mv;

    // ---- Phase A: row argmin (lane t = row t+1); 4 ranges, deep unroll
    float mv0 = INFV, mv1 = INFV, mv2 = INFV, mv3 = INFV;
    int   mj0 = 0,    mj1 = 0,    mj2 = 0,    mj3 = 0;
    #pragma unroll 9
    for (int n = 0; n < 225; ++n) {
        float c0 = cb[(size_t)(n      ) * Mv + t];
        float c1 = cb[(size_t)(n + 225) * Mv + t];
        float c2 = cb[(size_t)(n + 450) * Mv + t];
        float c3 = cb[(size_t)(n + 675) * Mv + t];
        if (c0 < mv0) { mv0 = c0; mj0 = n;       }
        if (c1 < mv1) { mv1 = c1; mj1 = n + 225; }
        if (c2 < mv2) { mv2 = c2; mj2 = n + 450; }
        if (c3 < mv3) { mv3 = c3; mj3 = n + 675; }
    }
    float rowmin = mv0; int rown = mj0;
    if (mv1 < rowmin) { rowmin = mv1; rown = mj1; }
    if (mv2 < rowmin) { rowmin = mv2; rown = mj2; }
    if (mv3 < rowmin) { rowmin = mv3; rown = mj3; }

    float u_reg = rowmin;            // lane l holds u[l+1]
    const int jcol = rown + 1;       // column index in 1..900

    // ---- Phase B: duplicate detection (first occurrence wins)
    bool isdup = false;
    #pragma unroll
    for (int s = 1; s < 64; ++s) {
        int oj = __shfl(jcol, (t + 64 - s) & 63, 64);
        isdup |= (oj == jcol) && (s <= t);
    }
    unsigned long long pending = __ballot(isdup);

    int   p_reg[KREG], way_reg[KREG];
    float v_reg[KREG], minv[KREG], crow[KREG];
    #pragma unroll
    for (int k = 0; k < KREG; k++) { p_reg[k] = 0; way_reg[k] = 0; v_reg[k] = 0.f; }

    int rowcol = isdup ? 0 : jcol;   // lane i: column assigned to row i+1

    // scatter winners into distributed p[]
    #pragma unroll 8
    for (int i = 0; i < 64; ++i) {
        int jb = __shfl(jcol, i, 64);
        if (!((pending >> i) & 1ull) && t == (jb & 63))
            SET15(p_reg, jb >> 6, i + 1);
    }

    // ---- Phase C: Dijkstra phases for conflicted rows only
    while (pending) {
        const int i1v = __ffsll(pending);    // 1-based free row
        pending &= pending - 1;

        unsigned usedMask = (t == 0) ? 1u : 0u;   // dummy col 0 used
        unsigned long long rowMask = 0;
        #pragma unroll
        for (int k = 0; k < KREG; k++) minv[k] = INFV;

        int j0 = 0;
        int i0 = i1v;

        // initial gather for row i0; j==0 and j>=NCOLS slots get BIGV
        #pragma unroll
        for (int k = 0; k < KREG; k++) {
            int j = t + (k << 6);
            crow[k] = (j >= 1 && j < NCOLS)
                      ? cb[(((size_t)(j - 1)) << 6) + (i0 - 1)] : BIGV;
        }

        while (true) {
            rowMask |= 1ull << (i0 - 1);
            const int sl = __builtin_amdgcn_readfirstlane(i0 - 1);
            const float u_i0 = __int_as_float(
                __builtin_amdgcn_readlane(__float_as_int(u_reg), sl));

            // scan: sentinel-masked (R6-verified), 3-way split (R8-verified)
            float bv0 = INFV, bv1 = INFV, bv2 = INFV;
            int   bk0 = 0,    bk1 = 5,    bk2 = 10;
            #pragma unroll
            for (int k = 0; k < 5; k++) {
                float cur = (crow[k] - u_i0) - v_reg[k];
                if (cur < minv[k]) { minv[k] = cur; way_reg[k] = j0; }
                if (minv[k] < bv0) { bv0 = minv[k]; bk0 = k; }
            }
            #pragma unroll
            for (int k = 5; k < 10; k++) {
                float cur = (crow[k] - u_i0) - v_reg[k];
                if (cur < minv[k]) { minv[k] = cur; way_reg[k] = j0; }
                if (minv[k] < bv1) { bv1 = minv[k]; bk1 = k; }
            }
            #pragma unroll
            for (int k = 10; k < KREG; k++) {
                float cur = (crow[k] - u_i0) - v_reg[k];
                if (cur < minv[k]) { minv[k] = cur; way_reg[k] = j0; }
                if (minv[k] < bv2) { bv2 = minv[k]; bk2 = k; }
            }
            if (bv1 < bv0) { bv0 = bv1; bk0 = bk1; }
            if (bv2 < bv0) { bv0 = bv2; bk0 = bk2; }

            // fused packed reduce (R10-verified): delta, j1, inext at once
            int pcand; SELTREE15(p_reg, bk0, pcand);
            unsigned hi = f2s(bv0);
            unsigned lo = ((unsigned)(t + (bk0 << 6)) << 7) | (unsigned)pcand;
            wave_min_pair(hi, lo);
            const float delta = s2f(hi);
            const int   j1    = (int)(lo >> 7);
            const int   inext = (int)(lo & 0x7fu);

            const int k1 = j1 >> 6, l1 = j1 & 63;   // uniform (SGPR)

            // prefetch next row: RAW loads only (R7/R8 lesson) — vmcnt sinks
            // into the next scan, covered by the update pass below.
            const bool newbit = (t == l1);
            unsigned newUsed = usedMask | (newbit ? (1u << k1) : 0u);
            if (inext != 0) {
                const int src = inext - 1;
                #pragma unroll
                for (int k = 0; k < KREG; k++) {
                    int j = t + (k << 6);
                    bool valid = (j >= 1 && j < NCOLS) && !((newUsed >> k) & 1u);
                    crow[k] = valid
                              ? cb[(((size_t)(j - 1)) << 6) + src] : BIGV;
                }
            }

            // dual/distance updates (reference order; latency cover)
            if ((rowMask >> t) & 1ull) u_reg += delta;
            #pragma unroll
            for (int k = 0; k < KREG; k++) {
                bool used  = (usedMask >> k) & 1u;
                bool isnew = newbit && (k == k1);
                v_reg[k] = used ? v_reg[k] - delta : v_reg[k];
                float mupd = used ? minv[k] : minv[k] - delta;
                minv[k] = isnew ? INFV : mupd;
            }
            usedMask = newUsed;

            j0 = j1;
            i0 = inext;
            if (i0 == 0) break;              // free column reached
        }

        // backtrack: reassign columns along augmenting path
        while (j0 != 0) {
            const int k0 = j0 >> 6, l0 = j0 & 63;
            int wtmp; SEL15(way_reg, k0, wtmp);
            const int jprev = __shfl(wtmp, l0, 64);
            int pv;
            if (jprev == 0) {
                pv = i1v;
            } else {
                int ptmp2; SEL15(p_reg, jprev >> 6, ptmp2);
                pv = __shfl(ptmp2, jprev & 63, 64);
            }
            if (t == l0) SET15(p_reg, k0, pv);
            if (t == pv - 1) rowcol = j0;    // maintain row->column mirror
            j0 = jprev;
        }
    }

    outPred[b * Mv + t] = (float)(rowcol - 1);
    outTgt[b * Mv + t]  = (float)t;
}

// ---------------------------------------------------------------------------
extern "C" void kernel_launch(void* const* d_in, const int* in_sizes, int n_in,
                              void* d_out, int out_size, void* d_ws, size_t ws_size,
                              hipStream_t stream)
{
    (void)in_sizes; (void)n_in; (void)out_size; (void)d_ws; (void)ws_size;

    const float* logits  = (const float*)d_in[0];   // [64,900,128] f32
    const float* corners = (const float*)d_in[1];   // [64,900,8,3] f32
    const int*   labels  = (const int*)  d_in[2];   // [64,64] i32
    const float* boxes   = (const float*)d_in[3];   // [64,64,7] f32

    float* out  = (float*)d_out;
    float* Cc   = out;                               // [64,900,64]
    float* pred = out + (size_t)Bv * Nv * Mv;        // [64,64] as f32
    float* tgt  = pred + (size_t)Bv * Mv;            // [64,64] as f32

    cost_kernel<<<dim3(Nv, Bv), 64, 0, stream>>>(logits, corners, labels, boxes, Cc);
    lsa_kernel<<<Bv, 64, 0, stream>>>(Cc, pred, tgt);
}